// Round 1
// baseline (641.753 us; speedup 1.0000x reference)
//
#include <hip/hip_runtime.h>

typedef __attribute__((ext_vector_type(8))) short short8;
typedef __attribute__((ext_vector_type(4))) float f32x4;

#define LDX 40   // xs row stride (bf16 elems): 80 B -> 16B-aligned rows, <=2-way bank alias
#define LDW 40   // ws row stride
#define LDP 72   // ps row stride: 144 B rows, 16B aligned

__device__ __forceinline__ ushort f2bf(float f) {
  unsigned u = __builtin_bit_cast(unsigned, f);
  u = (u + 0x7fffu + ((u >> 16) & 1u)) >> 16;   // RNE
  return (ushort)u;
}

// ---- kernel 0: pack Wq,Wk,Wv (fp32 [384][64]) -> Wt bf16 [192][384], row n = out channel
// n 0..63 -> Q, 64..127 -> K, 128..191 -> V ; Wt[n][c] = W[c][n%64]
__global__ void prep_w(const float* __restrict__ Wk, const float* __restrict__ Wq,
                       const float* __restrict__ Wv, ushort* __restrict__ Wt) {
  int n = blockIdx.x;        // 0..191
  int c = threadIdx.x;       // 0..383
  const float* src = (n < 64) ? Wq : ((n < 128) ? Wk : Wv);
  int h = n & 63;
  Wt[n * 384 + c] = f2bf(src[c * 64 + h]);
}

// ---- kernel A: qkv = x @ [Wq|Wk|Wv], swapped-operand MFMA (A=Wt, B=x)
// block: 256 thr (4 waves), tile 192n x 128t, BK=32, 12 k-iters
// outputs: qg,kg as bf16 [B*T][64]; v transposed vtg bf16 [B][64][256]
__global__ __launch_bounds__(256) void qkv_gemm(const float* __restrict__ x,
    const ushort* __restrict__ Wt, ushort* __restrict__ qg,
    ushort* __restrict__ kg, ushort* __restrict__ vtg) {
  __shared__ ushort xs[128 * LDX];
  __shared__ ushort ws[192 * LDW];
  const int tid = threadIdx.x;
  const int wave = tid >> 6;
  const int lane = tid & 63;
  const int quad = lane >> 4;
  const int l16 = lane & 15;
  const long t0 = (long)blockIdx.x * 128;

  f32x4 acc[12][2];
#pragma unroll
  for (int i = 0; i < 12; ++i)
#pragma unroll
    for (int j = 0; j < 2; ++j) acc[i][j] = f32x4{0.f, 0.f, 0.f, 0.f};

  for (int c0 = 0; c0 < 384; c0 += 32) {
    __syncthreads();   // protect previous iter's LDS reads (WAR)
    // stage x: 128x32 fp32 -> bf16 LDS (1024 float4, 4/thread)
#pragma unroll
    for (int i = 0; i < 4; ++i) {
      int idx = i * 256 + tid;
      int row = idx >> 3, c4 = idx & 7;
      float4 f = *(const float4*)(x + (t0 + row) * 384 + c0 + c4 * 4);
      ushort4 h;
      h.x = f2bf(f.x); h.y = f2bf(f.y); h.z = f2bf(f.z); h.w = f2bf(f.w);
      *(ushort4*)(&xs[row * LDX + c4 * 4]) = h;
    }
    // stage Wt chunk: 192x32 bf16 (768 x 16B, 3/thread)
#pragma unroll
    for (int i = 0; i < 3; ++i) {
      int idx = i * 256 + tid;
      int n = idx >> 2, cc = idx & 3;
      uint4 d = *(const uint4*)(Wt + n * 384 + c0 + cc * 8);
      *(uint4*)(&ws[n * LDW + cc * 8]) = d;
    }
    __syncthreads();
    // each wave: 192n x 32t slab (t rows wave*32..+31)
    short8 bfr[2];
#pragma unroll
    for (int tt = 0; tt < 2; ++tt)
      bfr[tt] = *(const short8*)(&xs[(wave * 32 + tt * 16 + l16) * LDX + quad * 8]);
#pragma unroll
    for (int mt = 0; mt < 12; ++mt) {
      short8 a = *(const short8*)(&ws[(mt * 16 + l16) * LDW + quad * 8]);
      acc[mt][0] = __builtin_amdgcn_mfma_f32_16x16x32_bf16(a, bfr[0], acc[mt][0], 0, 0, 0);
      acc[mt][1] = __builtin_amdgcn_mfma_f32_16x16x32_bf16(a, bfr[1], acc[mt][1], 0, 0, 0);
    }
  }
  // epilogue: D C-layout -> row = out-channel (quad*4+reg), col = token (l16)
#pragma unroll
  for (int mt = 0; mt < 12; ++mt) {
    const int sel = mt >> 2;                 // 0:q 1:k 2:v
    const int hb = (mt & 3) * 16 + quad * 4; // channel base within the 64
#pragma unroll
    for (int tt = 0; tt < 2; ++tt) {
      long tg = t0 + wave * 32 + tt * 16 + l16;
      if (sel < 2) {
        ushort4 h;
        h.x = f2bf(acc[mt][tt][0]); h.y = f2bf(acc[mt][tt][1]);
        h.z = f2bf(acc[mt][tt][2]); h.w = f2bf(acc[mt][tt][3]);
        ushort* dst = (sel == 0 ? qg : kg) + tg * 64 + hb;
        *(ushort4*)dst = h;                  // 4 consecutive h -> 8 B store
      } else {
        long b = tg >> 8;
        int tb = (int)(tg & 255);
#pragma unroll
        for (int r = 0; r < 4; ++r)
          vtg[b * 16384 + (long)(hb + r) * 256 + tb] = f2bf(acc[mt][tt][r]);
      }
    }
  }
}

// ---- kernel B: causal flash attention. 1 wave per (qb, b). grid (4, 1024).
__global__ __launch_bounds__(64, 2) void attn(const ushort* __restrict__ qg,
    const ushort* __restrict__ kg, const ushort* __restrict__ vtg,
    float* __restrict__ out) {
  __shared__ ushort ps[16 * LDP];            // P tile: C-layout -> A-layout transform
  const int lane = threadIdx.x;
  const int quad = lane >> 4;
  const int l16 = lane & 15;
  const int qb = blockIdx.x;                 // query block (64 rows)
  const int b = blockIdx.y;
  const long qbase = (long)b * 256 + qb * 64;

  // resident Q fragments: A[m=l16][k = kk*32 + quad*8 + j]
  short8 qf[4][2];
#pragma unroll
  for (int mt = 0; mt < 4; ++mt)
#pragma unroll
    for (int kk = 0; kk < 2; ++kk)
      qf[mt][kk] = *(const short8*)(qg + (qbase + mt * 16 + l16) * 64 + kk * 32 + quad * 8);

  f32x4 O[4][4];
  float m_s[4][4], l_s[4][4];                // per-lane stats for rows quad*4+r of each mt
#pragma unroll
  for (int mt = 0; mt < 4; ++mt) {
#pragma unroll
    for (int ht = 0; ht < 4; ++ht) O[mt][ht] = f32x4{0.f, 0.f, 0.f, 0.f};
#pragma unroll
    for (int r = 0; r < 4; ++r) { m_s[mt][r] = -3.0e38f; l_s[mt][r] = 0.f; }
  }
  const float sc = 0.125f * 1.44269504088896f;   // H^-0.5 * log2(e), softmax in exp2 domain

  for (int kb = 0; kb <= qb; ++kb) {
    const long kbase = (long)b * 256 + kb * 64;
    short8 kf[4][2];
#pragma unroll
    for (int nt = 0; nt < 4; ++nt)
#pragma unroll
      for (int kk = 0; kk < 2; ++kk)
        kf[nt][kk] = *(const short8*)(kg + (kbase + nt * 16 + l16) * 64 + kk * 32 + quad * 8);
    short8 vf[2][4];                         // B[k=key][n=h] from v^T rows
#pragma unroll
    for (int kk = 0; kk < 2; ++kk)
#pragma unroll
      for (int ht = 0; ht < 4; ++ht)
        vf[kk][ht] = *(const short8*)(vtg + (long)b * 16384 + (ht * 16 + l16) * 256 +
                                      kb * 64 + kk * 32 + quad * 8);
    const bool diag = (kb == qb);
#pragma unroll
    for (int mt = 0; mt < 4; ++mt) {
      f32x4 S[4];
#pragma unroll
      for (int nt = 0; nt < 4; ++nt) {
        S[nt] = f32x4{0.f, 0.f, 0.f, 0.f};
#pragma unroll
        for (int kk = 0; kk < 2; ++kk)
          S[nt] = __builtin_amdgcn_mfma_f32_16x16x32_bf16(qf[mt][kk], kf[nt][kk], S[nt], 0, 0, 0);
      }
      // scale + causal mask (diag block only). S C-layout: row=quad*4+r (query), col=l16 (key)
      float s2[4][4];
#pragma unroll
      for (int nt = 0; nt < 4; ++nt)
#pragma unroll
        for (int r = 0; r < 4; ++r) {
          float v = S[nt][r] * sc;
          if (diag && (nt * 16 + l16) > (mt * 16 + quad * 4 + r)) v = -1.0e30f;
          s2[nt][r] = v;
        }
      // row max across 64 keys: 4 frags in-reg, then 16-lane shfl reduce (rows live in a quad)
      float mnew[4], alpha[4], rsum[4];
#pragma unroll
      for (int r = 0; r < 4; ++r)
        mnew[r] = fmaxf(fmaxf(s2[0][r], s2[1][r]), fmaxf(s2[2][r], s2[3][r]));
#pragma unroll
      for (int off = 8; off > 0; off >>= 1)
#pragma unroll
        for (int r = 0; r < 4; ++r)
          mnew[r] = fmaxf(mnew[r], __shfl_xor(mnew[r], off, 64));
#pragma unroll
      for (int r = 0; r < 4; ++r) {
        mnew[r] = fmaxf(mnew[r], m_s[mt][r]);
        alpha[r] = exp2f(m_s[mt][r] - mnew[r]);
        m_s[mt][r] = mnew[r];
        rsum[r] = 0.f;
      }
      // P = exp2(s2 - m); write to LDS in row-major for A-operand reads
#pragma unroll
      for (int nt = 0; nt < 4; ++nt)
#pragma unroll
        for (int r = 0; r < 4; ++r) {
          float p = exp2f(s2[nt][r] - mnew[r]);
          rsum[r] += p;
          ps[(quad * 4 + r) * LDP + nt * 16 + l16] = f2bf(p);
        }
#pragma unroll
      for (int off = 8; off > 0; off >>= 1)
#pragma unroll
        for (int r = 0; r < 4; ++r)
          rsum[r] += __shfl_xor(rsum[r], off, 64);
#pragma unroll
      for (int r = 0; r < 4; ++r)
        l_s[mt][r] = l_s[mt][r] * alpha[r] + rsum[r];
      __syncthreads();  // drain P writes before A-frag reads (single wave: just waitcnt)
      // rescale O, then O += P @ V
#pragma unroll
      for (int ht = 0; ht < 4; ++ht)
#pragma unroll
        for (int r = 0; r < 4; ++r) O[mt][ht][r] *= alpha[r];
      short8 aP[2];
#pragma unroll
      for (int kk = 0; kk < 2; ++kk)
        aP[kk] = *(const short8*)(&ps[l16 * LDP + kk * 32 + quad * 8]);
#pragma unroll
      for (int kk = 0; kk < 2; ++kk)
#pragma unroll
        for (int ht = 0; ht < 4; ++ht)
          O[mt][ht] = __builtin_amdgcn_mfma_f32_16x16x32_bf16(aP[kk], vf[kk][ht], O[mt][ht], 0, 0, 0);
      __syncthreads();  // reads done before next mt overwrites ps
    }
  }
  // epilogue: out fp32 [b][t][h]; O C-layout row=query(quad*4+r), col=h(l16)
#pragma unroll
  for (int mt = 0; mt < 4; ++mt)
#pragma unroll
    for (int r = 0; r < 4; ++r) {
      float inv = 1.0f / l_s[mt][r];
      long row = qbase + mt * 16 + quad * 4 + r;
#pragma unroll
      for (int ht = 0; ht < 4; ++ht)
        out[row * 64 + ht * 16 + l16] = O[mt][ht][r] * inv;
    }
}

extern "C" void kernel_launch(void* const* d_in, const int* in_sizes, int n_in,
                              void* d_out, int out_size, void* d_ws, size_t ws_size,
                              hipStream_t stream) {
  const float* x  = (const float*)d_in[0];
  const float* Wk = (const float*)d_in[1];
  const float* Wq = (const float*)d_in[2];
  const float* Wv = (const float*)d_in[3];
  float* out = (float*)d_out;

  // ws layout: Wt bf16 [192*384] @0 (147456 B, pad to 256 KiB), then q,k,v^T bf16 (32 MiB each)
  ushort* Wt  = (ushort*)d_ws;
  ushort* qg  = (ushort*)((char*)d_ws + (1 << 18));
  ushort* kg  = qg + 16777216;
  ushort* vtg = kg + 16777216;

  prep_w<<<dim3(192), dim3(384), 0, stream>>>(Wk, Wq, Wv, Wt);
  qkv_gemm<<<dim3(2048), dim3(256), 0, stream>>>(x, Wt, qg, kg, vtg);
  attn<<<dim3(4, 1024), dim3(64), 0, stream>>>(qg, kg, vtg, out);
}